// Round 9
// baseline (216.818 us; speedup 1.0000x reference)
//
#include <hip/hip_runtime.h>

#define S_TOT 16384
#define DD 15
#define L2E  1.4426950408889634f
#define L2E2 2.8853900817779268f

typedef __attribute__((ext_vector_type(8))) short short8v;
typedef __attribute__((ext_vector_type(4))) float f32x4;

__device__ __forceinline__ float rcp_(float x){ return __builtin_amdgcn_rcpf(x); }
__device__ __forceinline__ float ex2_(float x){
#if __has_builtin(__builtin_amdgcn_exp2f)
  return __builtin_amdgcn_exp2f(x);
#else
  return exp2f(x);
#endif
}
__device__ __forceinline__ unsigned short f2bfu(float f){
  unsigned u = __float_as_uint(f);
  return (unsigned short)((u + 0x7FFFu + ((u>>16)&1u)) >> 16);
}
__device__ __forceinline__ float bfu2f(unsigned short s){
  return __uint_as_float(((unsigned)s)<<16);
}

// ============ prep: 47 blocks x 256 (unchanged from round 8) ============
__global__ void __launch_bounds__(256)
prep_k(const float* __restrict__ W_ih, const float* __restrict__ b_ih,
       const float* __restrict__ b_hh, const float* __restrict__ Wf1,
       const float* __restrict__ bf1, const float* __restrict__ Wf2,
       const float* __restrict__ bf2,
       unsigned short* __restrict__ wsW, float* __restrict__ ws2) {
  const int tid = threadIdx.x, blk = blockIdx.x;
  if (blk < 15) {
    __shared__ float red[4][16];
    const int i = blk;
    float acc[16];
#pragma unroll
    for (int c = 0; c < 16; ++c) acc[c] = 0.f;
    for (int k = tid; k < 4096; k += 256) {
      const float w2 = Wf2[i*4096 + k];
      const float* f1 = Wf1 + k*15;
#pragma unroll
      for (int c = 0; c < 15; ++c) acc[c] = fmaf(w2, f1[c], acc[c]);
      acc[15] = fmaf(w2, bf1[k], acc[15]);
    }
#pragma unroll
    for (int c = 0; c < 16; ++c) {
#pragma unroll
      for (int off = 32; off; off >>= 1) acc[c] += __shfl_xor(acc[c], off);
    }
    if ((tid & 63) == 0) {
#pragma unroll
      for (int c = 0; c < 16; ++c) red[tid>>6][c] = acc[c];
    }
    __syncthreads();
    if (tid < 16) {
      float s = red[0][tid] + red[1][tid] + red[2][tid] + red[3][tid];
      if (tid == 15) s += bf2[i];
      ws2[i*16 + tid] = s;
    }
  } else {
    const int p = (blk - 15)*256 + tid;   // 0..8191
    const int l32 = p & 31, tt = p >> 5;
    const int ct = tt & 15, w = tt >> 4;
    const int hk = l32 >> 4, c16 = l32 & 15;
    const int n = ct*16 + c16, g = n & 3, ul = n >> 2;
    const int row = g*1024 + w*64 + ul;
    const float sc = (g == 2) ? L2E2 : L2E;
    union { unsigned short us[8]; uint4 v; } u;
#pragma unroll
    for (int e = 0; e < 8; ++e) {
      const int k = hk*8 + e;
      const float val = (k < 15) ? W_ih[row*15 + k]*sc : (b_ih[row] + b_hh[row])*sc;
      u.us[e] = f2bfu(val);
    }
    *(uint4*)(wsW + p*8) = u.v;
  }
}

// ============ scan: 512 blocks x 1024 thr, CC=32, 2 blocks/CU ============
// LDS (bytes): total 71744 -> 2 blocks/CU (143.5KB of 160KB)
#define OFF_PRE  0        // 16 waves x (8 rows x 264 ushort = 528B) = 67584
#define PW_STR   4224
#define OFF_XST  67584    // 48 rows x 16 ushort (k15 = 1.0) = 1536
#define OFF_FST  69120    // 32 rows x 16 ushort (k15 = 1.0) = 1024
#define OFF_M2   70144    // 15x16 floats (col15 = cf) = 960
#define OFF_SLOT 71104    // float[2][16] = 128
#define OFF_P2   71232    // float[2][16][4] = 512
#define SMEM_TOT 71744

// fused-rcp cell: 5 ex2 + 3 rcp (was 5+5)
#define CELL(G, HV, CV, CNEW, PV) {                               \
  float pi_ = __uint_as_float((G).x << 16);                       \
  float pf_ = __uint_as_float((G).x & 0xFFFF0000u);               \
  float pg_ = __uint_as_float((G).y << 16);                       \
  float po_ = __uint_as_float((G).y & 0xFFFF0000u);               \
  float ea_ = ex2_(-fmaf(whhx, (HV), pi_));                       \
  float ef_ = ex2_(-fmaf(whhy, (HV), pf_));                       \
  float eg_ = ex2_( fmaf(whhz, (HV), pg_));                       \
  float eo_ = ex2_(-fmaf(whhw, (HV), po_));                       \
  float sf_ = rcp_(1.f + ef_);                                    \
  float rig_ = rcp_((1.f + ea_)*(1.f + eg_));                     \
  CNEW = fmaf(sf_, (CV), (eg_ - 1.f)*rig_);                       \
  float ec_ = ex2_((CNEW)*L2E2);                                  \
  float roc_ = rcp_((1.f + eo_)*(1.f + ec_));                     \
  PV = wr * ((ec_ - 1.f)*roc_); }

extern "C" __global__ void __launch_bounds__(1024, 8)
lstm_scan_k(const float* __restrict__ x, const float* __restrict__ W_hh,
            const float* __restrict__ W_hr,
            const unsigned short* __restrict__ wsW, const float* __restrict__ ws2,
            float* __restrict__ out) {
  extern __shared__ char smem[];
  unsigned short* xst = (unsigned short*)(smem + OFF_XST);
  unsigned short* fst = (unsigned short*)(smem + OFF_FST);
  float* m2f  = (float*)(smem + OFF_M2);
  float* slot = (float*)(smem + OFF_SLOT);
  float* p2f  = (float*)(smem + OFF_P2);

  const int j = threadIdx.x;
  const int l = j & 63, w = j >> 6;
  const int r16 = l & 15, hk = l >> 4;
  const int blk = blockIdx.x;
  const int t0 = blk * 32;
  char* myPre = smem + OFF_PRE + w*PW_STR;

  // ---- phase A: stage x rows (t0-16 .. t0+31), M2, forecasts ----
  if (j < 768) {
    const int r = j >> 4, k = j & 15;
    const int t = t0 - 16 + r;
    const float v = (k == 15) ? 1.f : ((t >= 0) ? x[t*DD + k] : 0.f);
    xst[j] = f2bfu(v);
  }
  if (j < 240) m2f[j] = ws2[j];
  __syncthreads();
  if (j < 480) {
    const int tf = j/15, i = j - tf*15;
    float acc = m2f[i*16 + 15];
#pragma unroll
    for (int m = 0; m < DD; ++m) acc = fmaf(m2f[i*16+m], bfu2f(xst[(16+tf)*16 + m]), acc);
    out[2*S_TOT + (t0 + tf)*DD + i] = acc;
    fst[tf*16 + i] = f2bfu(acc);
  } else if (j < 512) {
    fst[(j - 480)*16 + 15] = 0x3F80;  // bias slot = 1.0
  }

  const float whhx = W_hh[j]*L2E, whhy = W_hh[1024+j]*L2E,
              whhz = W_hh[2048+j]*L2E2, whhw = W_hh[3072+j]*L2E;
  const float wr = W_hr[j];
  __syncthreads();

  // ---- per-wave window GEMM: 4-step windows. rows 0-3 = x (cell1), 4-7 = f (cell2).
  auto stage_window = [&](int wi) {
    const int rm = r16 & 3, half = (r16 >> 2) & 1;
    const unsigned short* rp;
    if (wi < 4) rp = xst + (4*wi + rm)*16;            // warm: x only (dup halves)
    else rp = half ? (fst + (4*(wi-4) + rm)*16)
                   : (xst + (16 + 4*(wi-4) + rm)*16);
    short8v a = (short8v)0;
    if (l < 32) a = *(const short8v*)((const char*)rp + hk*16);
#pragma unroll
    for (int ct = 0; ct < 16; ++ct) {
      short8v bb = (short8v)0;
      if (l < 32) bb = ((const short8v*)wsW)[(w*16 + ct)*32 + l];
      f32x4 z = {0.f, 0.f, 0.f, 0.f};
      f32x4 d = __builtin_amdgcn_mfma_f32_16x16x32_bf16(a, bb, z, 0, 0, 0);
      if (l < 32) {
        char* cb = myPre + (ct*16 + r16)*2;
#pragma unroll
        for (int r2 = 0; r2 < 4; ++r2)
          *(unsigned short*)(cb + (4*hk + r2)*528) = f2bfu(d[r2]);
      }
    }
  };

  float h = 0.f, cst = 0.f;
  int buf = 0;
  const float lv = (blk == 0) ? 0.f : 1.f;
  float hh[4], chh[4];

  for (int wi = 0; wi < 12; ++wi) {
    stage_window(wi);
    const bool warm = (wi < 4);
#pragma unroll
    for (int r = 0; r < 4; ++r) {
      const uint2 g1 = *(const uint2*)(myPre + r*528 + l*8);
      float cn, p1;
      CELL(g1, h, cst, cn, p1);
      if (warm) { cn *= lv; p1 *= lv; }
      cst = cn;
#pragma unroll
      for (int off = 32; off; off >>= 1) p1 += __shfl_xor(p1, off);
      if (l == 0) slot[buf*16 + w] = p1;
      __syncthreads();
      if (r == 0 && wi > 4 && j < 4) {     // publish previous window's fprog
        const float* pq = p2f + ((wi-1) & 1)*64;
        float s = 0.f;
#pragma unroll
        for (int w2 = 0; w2 < 16; ++w2) s += pq[w2*4 + j];
        out[S_TOT + t0 + 4*(wi-5) + j] = s;
      }
      const f32x4* pp = (const f32x4*)(slot + buf*16);
      const f32x4 q0 = pp[0], q1 = pp[1], q2 = pp[2], q3 = pp[3];
      h = (q0.x+q0.y+q0.z+q0.w) + (q1.x+q1.y+q1.z+q1.w)
        + (q2.x+q2.y+q2.z+q2.w) + (q3.x+q3.y+q3.z+q3.w);
      if (!warm) {
        hh[r] = h; chh[r] = cn;
        if (j == 0) out[t0 + 4*(wi-4) + r] = h;
      }
      buf ^= 1;
    }
    if (!warm) {
      // cell2 batch: rows 4-7, independent, consumes (h1,c1) history
      float p2r[4];
#pragma unroll
      for (int r = 0; r < 4; ++r) {
        const uint2 g2 = *(const uint2*)(myPre + (4+r)*528 + l*8);
        float d2;
        CELL(g2, hh[r], chh[r], d2, p2r[r]);
      }
#pragma unroll
      for (int r = 0; r < 4; ++r) {
#pragma unroll
        for (int off = 32; off; off >>= 1) p2r[r] += __shfl_xor(p2r[r], off);
      }
      if (l == 0) {
#pragma unroll
        for (int r = 0; r < 4; ++r) p2f[(wi & 1)*64 + w*4 + r] = p2r[r];
      }
    }
  }
  __syncthreads();
  if (j < 4) {
    const float* pq = p2f + (11 & 1)*64;
    float s = 0.f;
#pragma unroll
    for (int w2 = 0; w2 < 16; ++w2) s += pq[w2*4 + j];
    out[S_TOT + t0 + 28 + j] = s;
  }
}

extern "C" void kernel_launch(void* const* d_in, const int* in_sizes, int n_in,
                              void* d_out, int out_size, void* d_ws, size_t ws_size,
                              hipStream_t stream) {
  const float* x    = (const float*)d_in[0];
  const float* W_ih = (const float*)d_in[1];
  const float* W_hh = (const float*)d_in[2];
  const float* b_ih = (const float*)d_in[3];
  const float* b_hh = (const float*)d_in[4];
  const float* W_hr = (const float*)d_in[5];
  const float* Wf1  = (const float*)d_in[6];
  const float* bf1  = (const float*)d_in[7];
  const float* Wf2  = (const float*)d_in[8];
  const float* bf2  = (const float*)d_in[9];
  float* out = (float*)d_out;
  unsigned short* wsW = (unsigned short*)d_ws;
  float* ws2 = (float*)((char*)d_ws + 131072);

  hipLaunchKernelGGL(prep_k, dim3(47), dim3(256), 0, stream,
                     W_ih, b_ih, b_hh, Wf1, bf1, Wf2, bf2, wsW, ws2);
  (void)hipFuncSetAttribute((const void*)lstm_scan_k,
                            hipFuncAttributeMaxDynamicSharedMemorySize, SMEM_TOT);
  hipLaunchKernelGGL(lstm_scan_k, dim3(512), dim3(1024), SMEM_TOT, stream,
                     x, W_hh, W_hr, wsW, ws2, out);
}